// Round 1
// baseline (314.052 us; speedup 1.0000x reference)
//
#include <hip/hip_runtime.h>
#include <hip/hip_bf16.h>
#include <math.h>

#define FIN 128
#define H   64
#define C   40

// ---------------- kernels ----------------

// deg[n] = 1.0 (self-loop weight); also zero the 64-float colsum accumulator t
__global__ __launch_bounds__(256) void k_init(float* __restrict__ deg, float* __restrict__ t, int N) {
    int i = blockIdx.x * blockDim.x + threadIdx.x;
    if (i < N) deg[i] = 1.0f;
    if (i < H) t[i] = 0.0f;
}

// deg[dst[e]] += ew[e]
__global__ __launch_bounds__(256) void k_deg(const int* __restrict__ dst, const float* __restrict__ ew,
                                             float* __restrict__ deg, int E) {
    int e = blockIdx.x * blockDim.x + threadIdx.x;
    if (e < E) atomicAdd(&deg[dst[e]], ew[e]);
}

// deg -> dinv in place
__global__ __launch_bounds__(256) void k_dinv(float* __restrict__ deg, int N) {
    int i = blockIdx.x * blockDim.x + threadIdx.x;
    if (i < N) {
        float d = deg[i];
        deg[i] = (d > 0.0f) ? rsqrtf(fmaxf(d, 1e-12f)) : 0.0f;
    }
}

// h = x @ W1   ([N,128] x [128,64]) — 4 rows per 256-thread block
__global__ __launch_bounds__(256) void k_gemm1(const float* __restrict__ x, const float* __restrict__ W1,
                                               float* __restrict__ h, int N) {
    __shared__ float sW[FIN * H];   // 32 KB
    __shared__ float sx[4 * FIN];   // 2 KB
    int tid = threadIdx.x;
    for (int i = tid; i < FIN * H; i += 256) sW[i] = W1[i];
    int row0 = blockIdx.x * 4;
    for (int i = tid; i < 4 * FIN; i += 256) {
        int r = row0 + i / FIN;
        sx[i] = (r < N) ? x[(size_t)r * FIN + (i % FIN)] : 0.0f;
    }
    __syncthreads();
    int lr  = tid >> 6;   // 0..3 local row
    int col = tid & 63;   // 0..63
    int row = row0 + lr;
    float acc = 0.0f;
#pragma unroll 8
    for (int k = 0; k < FIN; ++k)
        acc += sx[lr * FIN + k] * sW[k * H + col];
    if (row < N) h[(size_t)row * H + col] = acc;
}

// zero agg (float4)
__global__ __launch_bounds__(256) void k_zero4(float4* __restrict__ p, int n4) {
    int i = blockIdx.x * blockDim.x + threadIdx.x;
    if (i < n4) p[i] = make_float4(0.f, 0.f, 0.f, 0.f);
}

// edge scatter: agg[dst] += dinv[src]*ew*dinv[dst] * h[src]; one wave (64 lanes) per edge
__global__ __launch_bounds__(256) void k_edge(const int* __restrict__ src, const int* __restrict__ dst,
                                              const float* __restrict__ ew, const float* __restrict__ dinv,
                                              const float* __restrict__ h, float* __restrict__ agg, int E) {
    long long i = (long long)blockIdx.x * blockDim.x + threadIdx.x;
    int e = (int)(i >> 6);
    int k = (int)(i & 63);
    if (e >= E) return;
    int s = src[e], d = dst[e];
    float nrm = dinv[s] * ew[e] * dinv[d];
    atomicAdd(&agg[(size_t)d * H + k], nrm * h[(size_t)s * H + k]);
}

// per-node: v = relu(agg + dinv^2*h + b1); colsum into t[64]
__global__ __launch_bounds__(256) void k_relu_colsum(const float* __restrict__ agg, const float* __restrict__ h,
                                                     const float* __restrict__ dinv, const float* __restrict__ b1,
                                                     float* __restrict__ t, int N) {
    __shared__ float sp[256];
    int tid = threadIdx.x;
    int k   = tid & 63;
    int sub = tid >> 6;   // 0..3
    float bk = b1[k];
    float acc = 0.0f;
    for (int n = blockIdx.x * 4 + sub; n < N; n += gridDim.x * 4) {
        float di = dinv[n];
        float v = agg[(size_t)n * H + k] + di * di * h[(size_t)n * H + k] + bk;
        acc += fmaxf(v, 0.0f);
    }
    sp[tid] = acc;
    __syncthreads();
    if (sub == 0) {
        float s = sp[k] + sp[64 + k] + sp[128 + k] + sp[192 + k];
        atomicAdd(&t[k], s);
    }
}

// s = t @ W2 + N*b2; ls = log_softmax(s)
__global__ __launch_bounds__(64) void k_final(const float* __restrict__ t, const float* __restrict__ W2,
                                              const float* __restrict__ b2, float* __restrict__ ls, int N) {
    __shared__ float s[C];
    __shared__ float red;
    int c = threadIdx.x;
    if (c < C) {
        float acc = (float)N * b2[c];
#pragma unroll
        for (int k = 0; k < H; ++k) acc += t[k] * W2[k * C + c];
        s[c] = acc;
    }
    __syncthreads();
    if (c == 0) {
        float m = s[0];
        for (int i = 1; i < C; ++i) m = fmaxf(m, s[i]);
        float se = 0.0f;
        for (int i = 0; i < C; ++i) se += expf(s[i] - m);
        red = m + logf(se);
    }
    __syncthreads();
    if (c < C) ls[c] = s[c] - red;
}

// broadcast ls (40 floats) to every row of out; float4 writes (40 % 4 == 0)
__global__ __launch_bounds__(256) void k_bcast(const float* __restrict__ ls, float4* __restrict__ out, int n4) {
    __shared__ float sl[C];
    if (threadIdx.x < C) sl[threadIdx.x] = ls[threadIdx.x];
    __syncthreads();
    int i = blockIdx.x * blockDim.x + threadIdx.x;
    if (i < n4) {
        int idx0 = (i % 10) * 4;   // (4*i) % 40
        float4 v;
        v.x = sl[idx0];
        v.y = sl[idx0 + 1];
        v.z = sl[idx0 + 2];
        v.w = sl[idx0 + 3];
        out[i] = v;
    }
}

// ---------------- launch ----------------

extern "C" void kernel_launch(void* const* d_in, const int* in_sizes, int n_in,
                              void* d_out, int out_size, void* d_ws, size_t ws_size,
                              hipStream_t stream) {
    const float* x   = (const float*)d_in[0];
    const int*   ei  = (const int*)d_in[1];   // [2,E] flat: src then dst
    const float* ew  = (const float*)d_in[2];
    const float* W1  = (const float*)d_in[3];
    const float* b1  = (const float*)d_in[4];
    const float* W2  = (const float*)d_in[5];
    const float* b2  = (const float*)d_in[6];
    float* out = (float*)d_out;

    const int N = in_sizes[0] / FIN;     // 50000
    const int E = in_sizes[2];           // 800000
    const int* src = ei;
    const int* dst = ei + E;

    // workspace layout (floats)
    float* ws   = (float*)d_ws;
    float* deg  = ws;                         // N  (becomes dinv in place)
    float* t    = ws + 50048;                 // 64
    float* ls   = ws + 50112;                 // 64
    float* h    = ws + 50176;                 // N*H
    float* agg  = h + (size_t)N * H;          // N*H

    k_init<<<(N + 255) / 256, 256, 0, stream>>>(deg, t, N);
    k_deg<<<(E + 255) / 256, 256, 0, stream>>>(dst, ew, deg, E);
    k_dinv<<<(N + 255) / 256, 256, 0, stream>>>(deg, N);

    k_gemm1<<<(N + 3) / 4, 256, 0, stream>>>(x, W1, h, N);

    int aggN4 = (N * H) / 4;
    k_zero4<<<(aggN4 + 255) / 256, 256, 0, stream>>>((float4*)agg, aggN4);

    long long ethreads = (long long)E * 64;
    int eblocks = (int)((ethreads + 255) / 256);
    k_edge<<<eblocks, 256, 0, stream>>>(src, dst, ew, deg, h, agg, E);

    k_relu_colsum<<<512, 256, 0, stream>>>(agg, h, deg, b1, t, N);

    k_final<<<1, 64, 0, stream>>>(t, W2, b2, ls, N);

    int n4 = out_size / 4;
    k_bcast<<<(n4 + 255) / 256, 256, 0, stream>>>(ls, (float4*)out, n4);
}

// Round 2
// 289.193 us; speedup vs baseline: 1.0860x; 1.0860x over previous
//
#include <hip/hip_runtime.h>
#include <hip/hip_bf16.h>
#include <math.h>

#define FIN 128
#define H   64
#define C   40
#define SCAN_B 256

// ---------------- kernels ----------------

// deg[n]=1.0 (self-loop), count[n]=0, t=0
__global__ __launch_bounds__(256) void k_init(float* __restrict__ deg, float* __restrict__ t,
                                              int* __restrict__ count, int N) {
    int i = blockIdx.x * blockDim.x + threadIdx.x;
    if (i < N) { deg[i] = 1.0f; count[i] = 0; }
    if (i < H) t[i] = 0.0f;
}

// histogram: deg[dst] += ew (float), count[dst]++ (int)
__global__ __launch_bounds__(256) void k_deg(const int* __restrict__ dst, const float* __restrict__ ew,
                                             float* __restrict__ deg, int* __restrict__ count, int E) {
    int e = blockIdx.x * blockDim.x + threadIdx.x;
    if (e < E) {
        int d = dst[e];
        atomicAdd(&deg[d], ew[e]);
        atomicAdd(&count[d], 1);
    }
}

// deg -> dinv in place
__global__ __launch_bounds__(256) void k_dinv(float* __restrict__ deg, int N) {
    int i = blockIdx.x * blockDim.x + threadIdx.x;
    if (i < N) {
        float d = deg[i];
        deg[i] = (d > 0.0f) ? rsqrtf(fmaxf(d, 1e-12f)) : 0.0f;
    }
}

// per-block exclusive scan of count -> offsets; block totals -> bsum
__global__ __launch_bounds__(SCAN_B) void k_scan1(const int* __restrict__ count, int* __restrict__ offsets,
                                                  int* __restrict__ bsum, int N) {
    __shared__ int tmp[SCAN_B];
    int tid = threadIdx.x;
    int i = blockIdx.x * SCAN_B + tid;
    int v = (i < N) ? count[i] : 0;
    tmp[tid] = v;
    __syncthreads();
    for (int off = 1; off < SCAN_B; off <<= 1) {
        int add = (tid >= off) ? tmp[tid - off] : 0;
        __syncthreads();
        tmp[tid] += add;
        __syncthreads();
    }
    if (i < N) offsets[i] = tmp[tid] - v;                 // exclusive within block
    if (tid == SCAN_B - 1) bsum[blockIdx.x] = tmp[tid];   // block total
}

// single-block exclusive scan of bsum (nb <= 256)
__global__ __launch_bounds__(SCAN_B) void k_scan2(int* __restrict__ bsum, int nb) {
    __shared__ int tmp[SCAN_B];
    int tid = threadIdx.x;
    int v = (tid < nb) ? bsum[tid] : 0;
    tmp[tid] = v;
    __syncthreads();
    for (int off = 1; off < SCAN_B; off <<= 1) {
        int add = (tid >= off) ? tmp[tid - off] : 0;
        __syncthreads();
        tmp[tid] += add;
        __syncthreads();
    }
    if (tid < nb) bsum[tid] = tmp[tid] - v;               // exclusive
}

// offsets += bsum[block]; cursor = offsets
__global__ __launch_bounds__(SCAN_B) void k_scan3(int* __restrict__ offsets, const int* __restrict__ bsum,
                                                  int* __restrict__ cursor, int N) {
    int i = blockIdx.x * SCAN_B + threadIdx.x;
    if (i < N) {
        int o = offsets[i] + bsum[blockIdx.x];
        offsets[i] = o;
        cursor[i] = o;
    }
}

// scatter edges into dst-sorted order; precompute full norm
__global__ __launch_bounds__(256) void k_fill(const int* __restrict__ src, const int* __restrict__ dst,
                                              const float* __restrict__ ew, const float* __restrict__ dinv,
                                              int* __restrict__ cursor, int* __restrict__ srcs,
                                              float* __restrict__ w, int E) {
    int e = blockIdx.x * blockDim.x + threadIdx.x;
    if (e >= E) return;
    int s = src[e], d = dst[e];
    int pos = atomicAdd(&cursor[d], 1);
    srcs[pos] = s;
    w[pos] = dinv[s] * ew[e] * dinv[d];
}

// h = x @ W1   ([N,128] x [128,64]) — 4 rows per 256-thread block
__global__ __launch_bounds__(256) void k_gemm1(const float* __restrict__ x, const float* __restrict__ W1,
                                               float* __restrict__ h, int N) {
    __shared__ float sW[FIN * H];   // 32 KB
    __shared__ float sx[4 * FIN];   // 2 KB
    int tid = threadIdx.x;
    for (int i = tid; i < FIN * H; i += 256) sW[i] = W1[i];
    int row0 = blockIdx.x * 4;
    for (int i = tid; i < 4 * FIN; i += 256) {
        int r = row0 + i / FIN;
        sx[i] = (r < N) ? x[(size_t)r * FIN + (i % FIN)] : 0.0f;
    }
    __syncthreads();
    int lr  = tid >> 6;
    int col = tid & 63;
    int row = row0 + lr;
    float acc = 0.0f;
#pragma unroll 8
    for (int k = 0; k < FIN; ++k)
        acc += sx[lr * FIN + k] * sW[k * H + col];
    if (row < N) h[(size_t)row * H + col] = acc;
}

// per-node aggregation (one wave per node) fused with relu+bias+self-loop+colsum
__global__ __launch_bounds__(256) void k_agg(const int* __restrict__ offsets, const int* __restrict__ srcs,
                                             const float* __restrict__ w, const float* __restrict__ h,
                                             const float* __restrict__ dinv, const float* __restrict__ b1,
                                             float* __restrict__ t, int N, int E) {
    __shared__ float sp[256];
    int tid = threadIdx.x;
    int k   = tid & 63;
    int sub = tid >> 6;
    float bk = b1[k];
    float csum = 0.0f;
    for (int n = blockIdx.x * 4 + sub; n < N; n += gridDim.x * 4) {
        int base = offsets[n];
        int end  = (n == N - 1) ? E : offsets[n + 1];
        float di = dinv[n];
        float acc = di * di * h[(size_t)n * H + k];      // self-loop term
        for (int j = base; j < end; ++j) {
            acc += w[j] * h[(size_t)srcs[j] * H + k];
        }
        csum += fmaxf(acc + bk, 0.0f);
    }
    sp[tid] = csum;
    __syncthreads();
    if (sub == 0) atomicAdd(&t[k], sp[k] + sp[64 + k] + sp[128 + k] + sp[192 + k]);
}

// s = t @ W2 + N*b2; ls = log_softmax(s)
__global__ __launch_bounds__(64) void k_final(const float* __restrict__ t, const float* __restrict__ W2,
                                              const float* __restrict__ b2, float* __restrict__ ls, int N) {
    __shared__ float s[C];
    __shared__ float red;
    int c = threadIdx.x;
    if (c < C) {
        float acc = (float)N * b2[c];
#pragma unroll
        for (int k = 0; k < H; ++k) acc += t[k] * W2[k * C + c];
        s[c] = acc;
    }
    __syncthreads();
    if (c == 0) {
        float m = s[0];
        for (int i = 1; i < C; ++i) m = fmaxf(m, s[i]);
        float se = 0.0f;
        for (int i = 0; i < C; ++i) se += expf(s[i] - m);
        red = m + logf(se);
    }
    __syncthreads();
    if (c < C) ls[c] = s[c] - red;
}

// broadcast ls (40 floats) to every row; float4 writes
__global__ __launch_bounds__(256) void k_bcast(const float* __restrict__ ls, float4* __restrict__ out, int n4) {
    __shared__ float sl[C];
    if (threadIdx.x < C) sl[threadIdx.x] = ls[threadIdx.x];
    __syncthreads();
    int i = blockIdx.x * blockDim.x + threadIdx.x;
    if (i < n4) {
        int idx0 = (i % 10) * 4;
        float4 v;
        v.x = sl[idx0]; v.y = sl[idx0 + 1]; v.z = sl[idx0 + 2]; v.w = sl[idx0 + 3];
        out[i] = v;
    }
}

// ---------------- launch ----------------

extern "C" void kernel_launch(void* const* d_in, const int* in_sizes, int n_in,
                              void* d_out, int out_size, void* d_ws, size_t ws_size,
                              hipStream_t stream) {
    const float* x   = (const float*)d_in[0];
    const int*   ei  = (const int*)d_in[1];
    const float* ew  = (const float*)d_in[2];
    const float* W1  = (const float*)d_in[3];
    const float* b1  = (const float*)d_in[4];
    const float* W2  = (const float*)d_in[5];
    const float* b2  = (const float*)d_in[6];
    float* out = (float*)d_out;

    const int N = in_sizes[0] / FIN;     // 50000
    const int E = in_sizes[2];           // 800000
    const int* src = ei;
    const int* dst = ei + E;

    // workspace layout (4-byte units)
    float* ws      = (float*)d_ws;
    float* deg     = ws;                              // N (becomes dinv)
    float* t       = ws + N;                          // 64
    float* ls      = t + H;                           // 64
    int*   count   = (int*)(ls + H);                  // N
    int*   offsets = count + N;                       // N
    int*   cursor  = offsets + N;                     // N
    int*   bsum    = cursor + N;                      // 256
    float* h       = (float*)(bsum + 256);            // N*H
    int*   srcs    = (int*)(h + (size_t)N * H);       // E
    float* w       = (float*)(srcs + E);              // E

    int nb = (N + SCAN_B - 1) / SCAN_B;               // 196 <= 256

    k_init<<<(N + 255) / 256, 256, 0, stream>>>(deg, t, count, N);
    k_deg<<<(E + 255) / 256, 256, 0, stream>>>(dst, ew, deg, count, E);
    k_dinv<<<(N + 255) / 256, 256, 0, stream>>>(deg, N);

    k_scan1<<<nb, SCAN_B, 0, stream>>>(count, offsets, bsum, N);
    k_scan2<<<1, SCAN_B, 0, stream>>>(bsum, nb);
    k_scan3<<<nb, SCAN_B, 0, stream>>>(offsets, bsum, cursor, N);

    k_fill<<<(E + 255) / 256, 256, 0, stream>>>(src, dst, ew, deg, cursor, srcs, w, E);

    k_gemm1<<<(N + 3) / 4, 256, 0, stream>>>(x, W1, h, N);

    k_agg<<<2048, 256, 0, stream>>>(offsets, srcs, w, h, deg, b1, t, N, E);

    k_final<<<1, 64, 0, stream>>>(t, W2, b2, ls, N);

    int n4 = out_size / 4;
    k_bcast<<<(n4 + 255) / 256, 256, 0, stream>>>(ls, (float4*)out, n4);
}

// Round 3
// 235.532 us; speedup vs baseline: 1.3334x; 1.2278x over previous
//
#include <hip/hip_runtime.h>
#include <hip/hip_bf16.h>
#include <math.h>

#define FIN 128
#define H   64
#define C   40
#define SCAN_B 256
#define GROWS 16

static __device__ __forceinline__ float bf2f(unsigned short u) {
    return __uint_as_float(((unsigned)u) << 16);
}
static __device__ __forceinline__ unsigned short f2bf(float f) {
    unsigned u = __float_as_uint(f);
    u += 0x7FFF + ((u >> 16) & 1);   // round-to-nearest-even
    return (unsigned short)(u >> 16);
}

// ---------------- kernels ----------------

// deg[n]=1.0 (self-loop), count[n]=0, t=0
__global__ __launch_bounds__(256) void k_init(float* __restrict__ deg, float* __restrict__ t,
                                              int* __restrict__ count, int N) {
    int i = blockIdx.x * blockDim.x + threadIdx.x;
    if (i < N) { deg[i] = 1.0f; count[i] = 0; }
    if (i < H) t[i] = 0.0f;
}

// histogram: deg[dst] += ew, count[dst]++
__global__ __launch_bounds__(256) void k_deg(const int* __restrict__ dst, const float* __restrict__ ew,
                                             float* __restrict__ deg, int* __restrict__ count, int E) {
    int e = blockIdx.x * blockDim.x + threadIdx.x;
    if (e < E) {
        int d = dst[e];
        atomicAdd(&deg[d], ew[e]);
        atomicAdd(&count[d], 1);
    }
}

// per-block exclusive scan of count -> offsets; block totals -> bsum
__global__ __launch_bounds__(SCAN_B) void k_scan1(const int* __restrict__ count, int* __restrict__ offsets,
                                                  int* __restrict__ bsum, int N) {
    __shared__ int tmp[SCAN_B];
    int tid = threadIdx.x;
    int i = blockIdx.x * SCAN_B + tid;
    int v = (i < N) ? count[i] : 0;
    tmp[tid] = v;
    __syncthreads();
    for (int off = 1; off < SCAN_B; off <<= 1) {
        int add = (tid >= off) ? tmp[tid - off] : 0;
        __syncthreads();
        tmp[tid] += add;
        __syncthreads();
    }
    if (i < N) offsets[i] = tmp[tid] - v;
    if (tid == SCAN_B - 1) bsum[blockIdx.x] = tmp[tid];
}

// single-block exclusive scan of bsum (nb <= 256)
__global__ __launch_bounds__(SCAN_B) void k_scan2(int* __restrict__ bsum, int nb) {
    __shared__ int tmp[SCAN_B];
    int tid = threadIdx.x;
    int v = (tid < nb) ? bsum[tid] : 0;
    tmp[tid] = v;
    __syncthreads();
    for (int off = 1; off < SCAN_B; off <<= 1) {
        int add = (tid >= off) ? tmp[tid - off] : 0;
        __syncthreads();
        tmp[tid] += add;
        __syncthreads();
    }
    if (tid < nb) bsum[tid] = tmp[tid] - v;
}

// offsets += bsum[block]; cursor = offsets; deg -> dinv in place (fused)
__global__ __launch_bounds__(SCAN_B) void k_scan3(int* __restrict__ offsets, const int* __restrict__ bsum,
                                                  int* __restrict__ cursor, float* __restrict__ deg, int N) {
    int i = blockIdx.x * SCAN_B + threadIdx.x;
    if (i < N) {
        int o = offsets[i] + bsum[blockIdx.x];
        offsets[i] = o;
        cursor[i] = o;
        float d = deg[i];
        deg[i] = (d > 0.0f) ? rsqrtf(fmaxf(d, 1e-12f)) : 0.0f;
    }
}

// scatter edges into dst-sorted order; pack (norm, src) into float2
__global__ __launch_bounds__(256) void k_fill(const int* __restrict__ src, const int* __restrict__ dst,
                                              const float* __restrict__ ew, const float* __restrict__ dinv,
                                              int* __restrict__ cursor, float2* __restrict__ ep, int E) {
    int e = blockIdx.x * blockDim.x + threadIdx.x;
    if (e >= E) return;
    int s = src[e], d = dst[e];
    int pos = atomicAdd(&cursor[d], 1);
    ep[pos] = make_float2(dinv[s] * ew[e] * dinv[d], __int_as_float(s));
}

// h = x @ W1 -> bf16; 16 rows per 256-thread block, 4 outputs/thread
__global__ __launch_bounds__(256) void k_gemm1(const float* __restrict__ x, const float* __restrict__ W1,
                                               unsigned short* __restrict__ hb, int N) {
    __shared__ float sW[FIN * H];       // 32 KB
    __shared__ float sx[GROWS * FIN];   // 8 KB
    int tid = threadIdx.x;
    for (int i = tid; i < FIN * H; i += 256) sW[i] = W1[i];
    int row0 = blockIdx.x * GROWS;
    for (int i = tid; i < GROWS * FIN; i += 256) {
        int r = row0 + i / FIN;
        sx[i] = (r < N) ? x[(size_t)r * FIN + (i % FIN)] : 0.0f;
    }
    __syncthreads();
    int col = tid & 63;
    int rq  = tid >> 6;   // 0..3 -> rows rq, rq+4, rq+8, rq+12
    float a0 = 0.f, a1 = 0.f, a2 = 0.f, a3 = 0.f;
#pragma unroll 4
    for (int kk = 0; kk < FIN; ++kk) {
        float wv = sW[kk * H + col];
        a0 += sx[rq * FIN + kk] * wv;
        a1 += sx[(rq + 4) * FIN + kk] * wv;
        a2 += sx[(rq + 8) * FIN + kk] * wv;
        a3 += sx[(rq + 12) * FIN + kk] * wv;
    }
    int r = row0 + rq;
    if (r < N)      hb[r * H + col]            = f2bf(a0);
    if (r + 4 < N)  hb[(r + 4) * H + col]      = f2bf(a1);
    if (r + 8 < N)  hb[(r + 8) * H + col]      = f2bf(a2);
    if (r + 12 < N) hb[(r + 12) * H + col]     = f2bf(a3);
}

// per-node aggregation (one wave per node), 4x unrolled edge loop,
// fused relu+bias+self-loop+colsum
__global__ __launch_bounds__(256) void k_agg(const int* __restrict__ offsets, const float2* __restrict__ ep,
                                             const unsigned short* __restrict__ hb,
                                             const float* __restrict__ dinv, const float* __restrict__ b1,
                                             float* __restrict__ t, int N, int E) {
    __shared__ float sp[256];
    int tid = threadIdx.x;
    int k   = tid & 63;
    int sub = tid >> 6;
    float bk = b1[k];
    float csum = 0.0f;
    for (int n = blockIdx.x * 4 + sub; n < N; n += gridDim.x * 4) {
        int base = offsets[n];
        int end  = (n == N - 1) ? E : offsets[n + 1];
        float di = dinv[n];
        float acc = di * di * bf2f(hb[n * H + k]);
        int j = base;
        for (; j + 4 <= end; j += 4) {
            float2 p0 = ep[j], p1 = ep[j + 1], p2 = ep[j + 2], p3 = ep[j + 3];
            int s0 = __float_as_int(p0.y), s1 = __float_as_int(p1.y);
            int s2 = __float_as_int(p2.y), s3 = __float_as_int(p3.y);
            float v0 = bf2f(hb[s0 * H + k]);
            float v1 = bf2f(hb[s1 * H + k]);
            float v2 = bf2f(hb[s2 * H + k]);
            float v3 = bf2f(hb[s3 * H + k]);
            acc += p0.x * v0;
            acc += p1.x * v1;
            acc += p2.x * v2;
            acc += p3.x * v3;
        }
        for (; j < end; ++j) {
            float2 p = ep[j];
            acc += p.x * bf2f(hb[__float_as_int(p.y) * H + k]);
        }
        csum += fmaxf(acc + bk, 0.0f);
    }
    sp[tid] = csum;
    __syncthreads();
    if (sub == 0) atomicAdd(&t[k], sp[k] + sp[64 + k] + sp[128 + k] + sp[192 + k]);
}

// s = t @ W2 + N*b2; ls = log_softmax(s)
__global__ __launch_bounds__(64) void k_final(const float* __restrict__ t, const float* __restrict__ W2,
                                              const float* __restrict__ b2, float* __restrict__ ls, int N) {
    __shared__ float s[C];
    __shared__ float red;
    int c = threadIdx.x;
    if (c < C) {
        float acc = (float)N * b2[c];
#pragma unroll
        for (int k = 0; k < H; ++k) acc += t[k] * W2[k * C + c];
        s[c] = acc;
    }
    __syncthreads();
    if (c == 0) {
        float m = s[0];
        for (int i = 1; i < C; ++i) m = fmaxf(m, s[i]);
        float se = 0.0f;
        for (int i = 0; i < C; ++i) se += expf(s[i] - m);
        red = m + logf(se);
    }
    __syncthreads();
    if (c < C) ls[c] = s[c] - red;
}

// broadcast ls (40 floats) to every row; float4 writes
__global__ __launch_bounds__(256) void k_bcast(const float* __restrict__ ls, float4* __restrict__ out, int n4) {
    __shared__ float sl[C];
    if (threadIdx.x < C) sl[threadIdx.x] = ls[threadIdx.x];
    __syncthreads();
    int i = blockIdx.x * blockDim.x + threadIdx.x;
    if (i < n4) {
        int idx0 = (i % 10) * 4;
        float4 v;
        v.x = sl[idx0]; v.y = sl[idx0 + 1]; v.z = sl[idx0 + 2]; v.w = sl[idx0 + 3];
        out[i] = v;
    }
}

// ---------------- launch ----------------

extern "C" void kernel_launch(void* const* d_in, const int* in_sizes, int n_in,
                              void* d_out, int out_size, void* d_ws, size_t ws_size,
                              hipStream_t stream) {
    const float* x   = (const float*)d_in[0];
    const int*   ei  = (const int*)d_in[1];
    const float* ew  = (const float*)d_in[2];
    const float* W1  = (const float*)d_in[3];
    const float* b1  = (const float*)d_in[4];
    const float* W2  = (const float*)d_in[5];
    const float* b2  = (const float*)d_in[6];
    float* out = (float*)d_out;

    const int N = in_sizes[0] / FIN;     // 50000
    const int E = in_sizes[2];           // 800000
    const int* src = ei;
    const int* dst = ei + E;

    // workspace layout (4-byte units)
    float* ws      = (float*)d_ws;
    float* deg     = ws;                              // N (becomes dinv)
    float* t       = ws + N;                          // 64
    float* ls      = t + H;                           // 64
    int*   count   = (int*)(ls + H);                  // N
    int*   offsets = count + N;                       // N
    int*   cursor  = offsets + N;                     // N
    int*   bsum    = cursor + N;                      // 256
    float2* ep     = (float2*)(bsum + 256);           // E (8B each)
    unsigned short* hb = (unsigned short*)(ep + E);   // N*H bf16

    int nb = (N + SCAN_B - 1) / SCAN_B;

    k_init<<<(N + 255) / 256, 256, 0, stream>>>(deg, t, count, N);
    k_deg<<<(E + 255) / 256, 256, 0, stream>>>(dst, ew, deg, count, E);

    k_scan1<<<nb, SCAN_B, 0, stream>>>(count, offsets, bsum, N);
    k_scan2<<<1, SCAN_B, 0, stream>>>(bsum, nb);
    k_scan3<<<nb, SCAN_B, 0, stream>>>(offsets, bsum, cursor, deg, N);

    k_fill<<<(E + 255) / 256, 256, 0, stream>>>(src, dst, ew, deg, cursor, ep, E);

    k_gemm1<<<(N + GROWS - 1) / GROWS, 256, 0, stream>>>(x, W1, hb, N);

    k_agg<<<2048, 256, 0, stream>>>(offsets, ep, hb, deg, b1, t, N, E);

    k_final<<<1, 64, 0, stream>>>(t, W2, b2, ls, N);

    int n4 = out_size / 4;
    k_bcast<<<(n4 + 255) / 256, 256, 0, stream>>>(ls, (float4*)out, n4);
}